// Round 4
// baseline (237.779 us; speedup 1.0000x reference)
//
#include <hip/hip_runtime.h>

// CNN_36644660970295: 16 steps of [wrap-pad, conv3x3 1->2ch, +b1, tanh,
// conv1x1 2->1ch, +b2, relu] on B=32, 512x512 fp32.
// Round 4: fuse 4 steps; 8-px strips; neighbor scalars via ds_bpermute
// (lane +/-1) instead of conflicted ds_read_b32; BUFW=76 bank decorrelation.

#define NN 512
#define TILE 64
#define BUFW 76                   // padded row stride (cols 0..71 live)
#define BUFH 72
#define BUFN (BUFW * BUFH)        // 5472 floats per buffer
#define NSTRIP 9                  // 8-px strips per row
#define WORK (70 * NSTRIP)        // 630 strips per step

typedef float f4 __attribute__((ext_vector_type(4)));

__device__ __forceinline__ float tanh_fast(float x) {
    // identical arithmetic to rounds 1-3 (bit-exact output)
    float e = __expf(2.0f * x);
    return 1.0f - 2.0f * __builtin_amdgcn_rcpf(e + 1.0f);
}

__device__ __forceinline__ float permf(int addr, float v) {
    return __builtin_bit_cast(float,
        __builtin_amdgcn_ds_bpermute(addr, __builtin_bit_cast(int, v)));
}

__global__ __launch_bounds__(256) void fused4(
    const float* __restrict__ in, float* __restrict__ out,
    const float* __restrict__ w1, const float* __restrict__ b1,
    const float* __restrict__ w2, const float* __restrict__ b2)
{
    __shared__ float lds[2 * BUFN];

    const int tid = threadIdx.x;
    const int wg  = blockIdx.x;
    const int tx  = wg & 7;
    const int ty  = (wg >> 3) & 7;
    const int b   = wg >> 6;
    const float* img = in + (size_t)b * (NN * NN);
    const int base_r = ty * TILE - 4;
    const int base_c = tx * TILE - 4;

    // ---- Stage 72 rows x 72 cols (wrap halo) into 76-stride buffer ----
    #pragma unroll
    for (int k = 0; k < 6; ++k) {
        int w = tid + 256 * k;
        if (k < 5 || w < 72 * 18) {
            int row = w / 18;
            int c4  = (w - row * 18) << 2;
            int gr  = (base_r + row) & (NN - 1);
            int gc  = (base_c + c4) & (NN - 1);
            *reinterpret_cast<f4*>(lds + row * BUFW + c4) =
                *reinterpret_cast<const f4*>(img + gr * NN + gc);
        }
    }

    // ---- Weights (uniform) ----
    float W1[2][3][3];
    #pragma unroll
    for (int ch = 0; ch < 2; ++ch)
        #pragma unroll
        for (int r = 0; r < 3; ++r)
            #pragma unroll
            for (int q = 0; q < 3; ++q)
                W1[ch][r][q] = w1[ch * 9 + r * 3 + q];
    const float B1_0 = b1[0], B1_1 = b1[1];
    const float W2_0 = w2[0], W2_1 = w2[1];
    const float B2   = b2[0];

    // ---- Per-k strip geometry (reused by all 4 steps) ----
    const int lane = tid & 63;
    int  offk[3];
    bool fixL[3], fixR[3];
    bool act2;
    #pragma unroll
    for (int k = 0; k < 3; ++k) {
        int w = tid + 256 * k;
        int r = w / 9;                 // window top row (output row = r+1)
        int c = w - r * 9;             // strip index 0..8
        offk[k] = r * BUFW + (c << 3);
        fixL[k] = (lane == 0)  && (c != 0);
        fixR[k] = (lane == 63) && (c != 8);
    }
    act2 = (tid + 512) < WORK;
    const int aU = ((lane + 63) & 63) << 2;   // bpermute addr: lane-1
    const int aD = ((lane + 1)  & 63) << 2;   // bpermute addr: lane+1

    __syncthreads();

    // ---- 4 fused steps ----
    #pragma unroll
    for (int s = 0; s < 4; ++s) {
        const int so  = (s & 1) * BUFN;          // src buffer offset
        const int dof = (BUFN - so) + BUFW;      // dst offset (row+1)
        #pragma unroll
        for (int k = 0; k < 3; ++k) {
            if (k < 2 || act2) {
                const float* p = lds + so + offk[k];
                float wnd[3][10];
                #pragma unroll
                for (int r = 0; r < 3; ++r) {
                    f4 u = *reinterpret_cast<const f4*>(p + r * BUFW);
                    f4 v = *reinterpret_cast<const f4*>(p + r * BUFW + 4);
                    float lf = permf(aU, v.w);   // neighbor strip's col c0-1
                    float rt = permf(aD, u.x);   // neighbor strip's col c0+8
                    if (fixL[k]) lf = p[r * BUFW - 1];
                    if (fixR[k]) rt = p[r * BUFW + 8];
                    wnd[r][0] = lf;
                    wnd[r][1] = u.x; wnd[r][2] = u.y; wnd[r][3] = u.z; wnd[r][4] = u.w;
                    wnd[r][5] = v.x; wnd[r][6] = v.y; wnd[r][7] = v.z; wnd[r][8] = v.w;
                    wnd[r][9] = rt;
                }
                float res[8];
                #pragma unroll
                for (int px = 0; px < 8; ++px) {
                    float a0 = B1_0, a1 = B1_1;
                    #pragma unroll
                    for (int q = 0; q < 3; ++q) {   // q outer, rows inner:
                        a0 = fmaf(W1[0][0][q], wnd[0][px + q], a0);  // same
                        a1 = fmaf(W1[1][0][q], wnd[0][px + q], a1);  // order
                        a0 = fmaf(W1[0][1][q], wnd[1][px + q], a0);  // as r3
                        a1 = fmaf(W1[1][1][q], wnd[1][px + q], a1);
                        a0 = fmaf(W1[0][2][q], wnd[2][px + q], a0);
                        a1 = fmaf(W1[1][2][q], wnd[2][px + q], a1);
                    }
                    float t0 = tanh_fast(a0);
                    float t1 = tanh_fast(a1);
                    float y  = fmaf(W2_0, t0, fmaf(W2_1, t1, B2));
                    res[px] = fmaxf(y, 0.0f);
                }
                float* q = lds + dof + offk[k];
                *reinterpret_cast<f4*>(q)     = (f4){res[0], res[1], res[2], res[3]};
                *reinterpret_cast<f4*>(q + 4) = (f4){res[4], res[5], res[6], res[7]};
            }
        }
        __syncthreads();
    }

    // ---- Writeout rows/cols 4..67 of buf0 ----
    float* og = out + (size_t)b * (NN * NN);
    #pragma unroll
    for (int k = 0; k < 4; ++k) {
        int w  = tid + 256 * k;
        int rr = w >> 4;                 // 0..63
        int c4 = (w & 15) << 2;          // 0..60
        f4 v = *reinterpret_cast<const f4*>(lds + (rr + 4) * BUFW + c4 + 4);
        *reinterpret_cast<f4*>(
            og + (size_t)(ty * TILE + rr) * NN + tx * TILE + c4) = v;
    }
}

extern "C" void kernel_launch(void* const* d_in, const int* in_sizes, int n_in,
                              void* d_out, int out_size, void* d_ws, size_t ws_size,
                              hipStream_t stream) {
    const float* x  = (const float*)d_in[0];
    const float* w1 = (const float*)d_in[1];
    const float* b1 = (const float*)d_in[2];
    const float* w2 = (const float*)d_in[3];
    const float* b2 = (const float*)d_in[4];

    float* A = (float*)d_ws;    // ping
    float* B = (float*)d_out;   // pong (final group lands here)

    dim3 grid(32 * 8 * 8), block(256);   // 2048 workgroups

    fused4<<<grid, block, 0, stream>>>(x, A, w1, b1, w2, b2);
    fused4<<<grid, block, 0, stream>>>(A, B, w1, b1, w2, b2);
    fused4<<<grid, block, 0, stream>>>(B, A, w1, b1, w2, b2);
    fused4<<<grid, block, 0, stream>>>(A, B, w1, b1, w2, b2);
}

// Round 5
// 200.535 us; speedup vs baseline: 1.1857x; 1.1857x over previous
//
#include <hip/hip_runtime.h>

// CNN_36644660970295: 16 steps of [wrap-pad, conv3x3 1->2ch, +b1, tanh,
// conv1x1 2->1ch, +b2, relu] on B=32, 512x512 fp32.
// Round 5: 512-thread blocks (24 waves/CU @ 3 WG); trans diet (shared rcp,
// exp2-folded weights, affine folded into conv2). Same fused-4 structure.

#define NN 512
#define TILE 64
#define BUFW 76                   // padded row stride (cols 0..71 live)
#define BUFH 72
#define BUFN (BUFW * BUFH)        // 5472 floats per buffer
#define WORK (70 * 9)             // 630 8-px strips per step
#define NTHR 512

typedef float f4 __attribute__((ext_vector_type(4)));

#define TWO_LOG2E 2.8853900817779268f   // 2*log2(e)

__device__ __forceinline__ float permf(int addr, float v) {
    return __builtin_bit_cast(float,
        __builtin_amdgcn_ds_bpermute(addr, __builtin_bit_cast(int, v)));
}

__global__ __launch_bounds__(NTHR, 6) void fused4(
    const float* __restrict__ in, float* __restrict__ out,
    const float* __restrict__ w1, const float* __restrict__ b1,
    const float* __restrict__ w2, const float* __restrict__ b2)
{
    __shared__ float lds[2 * BUFN];

    const int tid = threadIdx.x;
    const int wg  = blockIdx.x;
    const int tx  = wg & 7;
    const int ty  = (wg >> 3) & 7;
    const int b   = wg >> 6;
    const float* img = in + (size_t)b * (NN * NN);
    const int base_r = ty * TILE - 4;
    const int base_c = tx * TILE - 4;

    // ---- Stage 72 rows x 72 cols (wrap halo) into 76-stride buffer ----
    #pragma unroll
    for (int k = 0; k < 3; ++k) {
        int w = tid + NTHR * k;
        if (k < 2 || w < 72 * 18) {
            int row = w / 18;
            int c4  = (w - row * 18) << 2;
            int gr  = (base_r + row) & (NN - 1);
            int gc  = (base_c + c4) & (NN - 1);
            *reinterpret_cast<f4*>(lds + row * BUFW + c4) =
                *reinterpret_cast<const f4*>(img + gr * NN + gc);
        }
    }

    // ---- Weights (uniform), pre-scaled for exp2-based tanh ----
    // tanh(a) with a = conv+b1:  e = exp2(a*2log2e); tanh = 1 - 2/(e+1)
    // y = w20*t0 + w21*t1 + b2 = V0/(e0+1)... folded: y = V0*inv0+V1*inv1+C2
    float W1[2][3][3];
    #pragma unroll
    for (int ch = 0; ch < 2; ++ch)
        #pragma unroll
        for (int r = 0; r < 3; ++r)
            #pragma unroll
            for (int q = 0; q < 3; ++q)
                W1[ch][r][q] = w1[ch * 9 + r * 3 + q] * TWO_LOG2E;
    const float B1_0 = b1[0] * TWO_LOG2E, B1_1 = b1[1] * TWO_LOG2E;
    const float V0 = -2.0f * w2[0], V1 = -2.0f * w2[1];
    const float C2 = w2[0] + w2[1] + b2[0];

    // ---- Per-k strip geometry (reused by all 4 steps) ----
    const int lane = tid & 63;
    int  offk[2];
    bool fixL[2], fixR[2];
    #pragma unroll
    for (int k = 0; k < 2; ++k) {
        int w = tid + NTHR * k;
        int r = w / 9;                 // window top row (output row = r+1)
        int c = w - r * 9;             // strip index 0..8
        offk[k] = r * BUFW + (c << 3);
        fixL[k] = (lane == 0)  && (c != 0);
        fixR[k] = (lane == 63) && (c != 8);
    }
    const bool act1 = tid < (WORK - NTHR);    // 118 threads
    const int aU = ((lane + 63) & 63) << 2;   // bpermute: lane-1
    const int aD = ((lane + 1)  & 63) << 2;   // bpermute: lane+1

    __syncthreads();

    // ---- 4 fused steps ----
    #pragma unroll
    for (int s = 0; s < 4; ++s) {
        const int so  = (s & 1) * BUFN;          // src buffer offset
        const int dof = (BUFN - so) + BUFW;      // dst offset (row+1)
        #pragma unroll
        for (int k = 0; k < 2; ++k) {
            if (k < 1 || act1) {
                const float* p = lds + so + offk[k];
                float wnd[3][10];
                #pragma unroll
                for (int r = 0; r < 3; ++r) {
                    f4 u = *reinterpret_cast<const f4*>(p + r * BUFW);
                    f4 v = *reinterpret_cast<const f4*>(p + r * BUFW + 4);
                    float lf = permf(aU, v.w);   // neighbor strip col c0-1
                    float rt = permf(aD, u.x);   // neighbor strip col c0+8
                    if (fixL[k]) lf = p[r * BUFW - 1];
                    if (fixR[k]) rt = p[r * BUFW + 8];
                    wnd[r][0] = lf;
                    wnd[r][1] = u.x; wnd[r][2] = u.y; wnd[r][3] = u.z; wnd[r][4] = u.w;
                    wnd[r][5] = v.x; wnd[r][6] = v.y; wnd[r][7] = v.z; wnd[r][8] = v.w;
                    wnd[r][9] = rt;
                }
                float res[8];
                #pragma unroll
                for (int px = 0; px < 8; ++px) {
                    float a0 = B1_0, a1 = B1_1;
                    #pragma unroll
                    for (int q = 0; q < 3; ++q) {
                        a0 = fmaf(W1[0][0][q], wnd[0][px + q], a0);
                        a1 = fmaf(W1[1][0][q], wnd[0][px + q], a1);
                        a0 = fmaf(W1[0][1][q], wnd[1][px + q], a0);
                        a1 = fmaf(W1[1][1][q], wnd[1][px + q], a1);
                        a0 = fmaf(W1[0][2][q], wnd[2][px + q], a0);
                        a1 = fmaf(W1[1][2][q], wnd[2][px + q], a1);
                    }
                    float e0 = __builtin_amdgcn_exp2f(a0);
                    float e1 = __builtin_amdgcn_exp2f(a1);
                    float d0 = e0 + 1.0f, d1 = e1 + 1.0f;
                    float rr = __builtin_amdgcn_rcpf(d0 * d1);
                    float inv0 = rr * d1, inv1 = rr * d0;
                    float y = fmaf(V0, inv0, fmaf(V1, inv1, C2));
                    res[px] = fmaxf(y, 0.0f);
                }
                float* q = lds + dof + offk[k];
                *reinterpret_cast<f4*>(q)     = (f4){res[0], res[1], res[2], res[3]};
                *reinterpret_cast<f4*>(q + 4) = (f4){res[4], res[5], res[6], res[7]};
            }
        }
        __syncthreads();
    }

    // ---- Writeout rows/cols 4..67 of buf0 ----
    float* og = out + (size_t)b * (NN * NN);
    #pragma unroll
    for (int k = 0; k < 2; ++k) {
        int w  = tid + NTHR * k;
        int rr = w >> 4;                 // 0..63
        int c4 = (w & 15) << 2;          // 0..60
        f4 v = *reinterpret_cast<const f4*>(lds + (rr + 4) * BUFW + c4 + 4);
        *reinterpret_cast<f4*>(
            og + (size_t)(ty * TILE + rr) * NN + tx * TILE + c4) = v;
    }
}

extern "C" void kernel_launch(void* const* d_in, const int* in_sizes, int n_in,
                              void* d_out, int out_size, void* d_ws, size_t ws_size,
                              hipStream_t stream) {
    const float* x  = (const float*)d_in[0];
    const float* w1 = (const float*)d_in[1];
    const float* b1 = (const float*)d_in[2];
    const float* w2 = (const float*)d_in[3];
    const float* b2 = (const float*)d_in[4];

    float* A = (float*)d_ws;    // ping
    float* B = (float*)d_out;   // pong (final group lands here)

    dim3 grid(32 * 8 * 8), block(NTHR);   // 2048 workgroups x 512

    fused4<<<grid, block, 0, stream>>>(x, A, w1, b1, w2, b2);
    fused4<<<grid, block, 0, stream>>>(A, B, w1, b1, w2, b2);
    fused4<<<grid, block, 0, stream>>>(B, A, w1, b1, w2, b2);
    fused4<<<grid, block, 0, stream>>>(A, B, w1, b1, w2, b2);
}